// Round 7
// baseline (577.328 us; speedup 1.0000x reference)
//
#include <hip/hip_runtime.h>
#include <math.h>

typedef __attribute__((ext_vector_type(8))) short short8;
typedef __attribute__((ext_vector_type(4))) float f32x4;
typedef unsigned short ushort_t;
typedef unsigned long long ull_t;

__device__ __forceinline__ float bf2f(ushort_t u) {
    return __uint_as_float(((unsigned int)u) << 16);
}
__device__ __forceinline__ ushort_t f2bf(float f) {
    unsigned int u = __float_as_uint(f);
    unsigned int r = u + 0x7fffu + ((u >> 16) & 1u);   // RTN-even
    return (ushort_t)(r >> 16);
}
__device__ __forceinline__ unsigned cvt_pk_bf16(float lo, float hi) {
    unsigned r;
    asm volatile("v_cvt_pk_bf16_f32 %0, %1, %2" : "=v"(r) : "v"(lo), "v"(hi));
    return r;
}

__device__ __forceinline__ void async_cp16(const void* g, void* l) {
    __builtin_amdgcn_global_load_lds((const __attribute__((address_space(1))) void*)g,
                                     (__attribute__((address_space(3))) void*)l, 16, 0, 0);
}

// tanh-form gelu via hardware exp: max abs err ~3e-4*|x|
__device__ __forceinline__ float fast_gelu(float v) {
    float u2 = 2.0f * v * (0.7978845608028654f + 0.0356774081f * v * v);
    float e = __expf(u2);
    float r = 1.0f / (e + 1.0f);
    return v - v * r;
}

// ---------------------------------------------------------------------------
// fused setup: 4 weight conversions + zero psum2/psq2 + expanded bias tables
// ---------------------------------------------------------------------------
__global__ __launch_bounds__(256) void conv_zero(
        const float* __restrict__ qkv_w, ushort_t* __restrict__ qkv_wb,
        const float* __restrict__ proj_w, ushort_t* __restrict__ proj_wb,
        const float* __restrict__ w1, ushort_t* __restrict__ w1b,
        const float* __restrict__ w2, ushort_t* __restrict__ w2b,
        float* __restrict__ psum2, float* __restrict__ psq2,
        const float* __restrict__ rpb1, const float* __restrict__ rpb2,
        float* __restrict__ tbl0, float* __restrict__ tbl1) {
    int i = blockIdx.x * 256 + threadIdx.x;
    if (i < 786432) {
        qkv_wb[i] = f2bf(qkv_w[i]);
    } else if (i < 1048576) {
        int j = i - 786432; proj_wb[j] = f2bf(proj_w[j]);
    } else if (i < 2097152) {
        int j = i - 1048576; w1b[j] = f2bf(w1[j]);
    } else if (i < 3145728) {
        int j = i - 2097152; w2b[j] = f2bf(w2[j]);
    } else if (i < 3153920) {
        int j = i - 3145728;       // [0, 8192)
        psum2[j] = 0.f; psq2[j] = 0.f;
    } else {
        int t = i - 3153920;       // [0, 163840)
        if (t < 32768) {
            int h = t >> 12, ij = t & 4095;
            int qi = ij >> 6, kj = ij & 63;
            int idx = ((qi >> 3) - (kj >> 3)) + ((qi & 7) - (kj & 7)) + 29;
            tbl0[t] = rpb1[idx * 8 + h];
        } else {
            int u = t - 32768;     // [0, 131072)
            int ij = u & 4095;
            int cls = (u >> 12) & 3;
            int h = u >> 14;
            int qi = ij >> 6, kj = ij & 63;
            int idx = ((qi >> 3) - (kj >> 3)) + ((qi & 7) - (kj & 7)) + 29;
            float v = rpb2[idx * 8 + h];
            int gh_i = (cls & 2) ? (((qi >> 3) < 4) ? 1 : 2) : 0;
            int gw_i = (cls & 1) ? (((qi & 7) < 4) ? 1 : 2) : 0;
            int gh_j = (cls & 2) ? (((kj >> 3) < 4) ? 1 : 2) : 0;
            int gw_j = (cls & 1) ? (((kj & 7) < 4) ? 1 : 2) : 0;
            if (gh_i * 3 + gw_i != gh_j * 3 + gw_j) v -= 100.f;
            tbl1[u] = v;
        }
    }
}

// ---------------------------------------------------------------------------
// style modulation
// ---------------------------------------------------------------------------
__global__ __launch_bounds__(256) void style_kernel(const float* __restrict__ style,
        const float* __restrict__ w1, const float* __restrict__ b1,
        const float* __restrict__ w2, const float* __restrict__ b2,
        float* __restrict__ s1, float* __restrict__ s2) {
    int t = blockIdx.x * 256 + threadIdx.x;
    int which = t >> 13;
    int idx = t & 8191;
    int b = idx >> 10, j = idx & 1023;
    const float* w = which ? w2 : w1;
    const float* bb = which ? b2 : b1;
    const float* st = style + b * 512;
    const float* wr = w + (size_t)j * 512;
    float acc = 0.f;
    for (int k = 0; k < 512; ++k) acc += st[k] * wr[k];
    float v = acc * 0.04419417382415922f + bb[j];
    (which ? s2 : s1)[idx] = v;
}

// ---------------------------------------------------------------------------
// instance-norm stats (adain1 path)
// ---------------------------------------------------------------------------
__global__ __launch_bounds__(512) void stats_part(const float* __restrict__ x,
        float* __restrict__ psum, float* __restrict__ psq) {
    int b = blockIdx.x >> 5;
    int ch = blockIdx.x & 31;
    int c = threadIdx.x;
    const float* p = x + ((size_t)b * 4096 + (size_t)ch * 128) * 512 + c;
    float s = 0.f, q = 0.f;
    for (int t = 0; t < 128; ++t) {
        float v = p[(size_t)t * 512];
        s += v; q += v * v;
    }
    psum[(size_t)blockIdx.x * 512 + c] = s;
    psq [(size_t)blockIdx.x * 512 + c] = q;
}

__global__ __launch_bounds__(256) void stats_fin(const float* __restrict__ psum,
        const float* __restrict__ psq, float* __restrict__ mean, float* __restrict__ rstd) {
    int i = blockIdx.x * 256 + threadIdx.x;
    int b = i >> 9, c = i & 511;
    float s = 0.f, q = 0.f;
    for (int ch = 0; ch < 32; ++ch) {
        s += psum[(size_t)(b * 32 + ch) * 512 + c];
        q += psq [(size_t)(b * 32 + ch) * 512 + c];
    }
    float m = s * (1.f / 4096.f);
    float v = q * (1.f / 4096.f) - m * m;
    mean[i] = m;
    rstd[i] = rsqrtf(v + 1e-5f);
}

__global__ __launch_bounds__(256) void stats_fin2(const float* __restrict__ psum2,
        const float* __restrict__ psq2, float* __restrict__ mean, float* __restrict__ rstd) {
    int i = blockIdx.x * 256 + threadIdx.x;   // 4096
    float m = psum2[i] * (1.f / 4096.f);
    float v = psq2[i] * (1.f / 4096.f) - m * m;
    mean[i] = m;
    rstd[i] = rsqrtf(v + 1e-5f);
}

// ---------------------------------------------------------------------------
// adain apply
// ---------------------------------------------------------------------------
__global__ __launch_bounds__(256) void adain_kernel(const float* __restrict__ x,
        const float* __restrict__ s, const float* __restrict__ mean,
        const float* __restrict__ rstd, ushort_t* __restrict__ xn) {
    size_t i4 = (size_t)blockIdx.x * 256 + threadIdx.x;
    size_t e = i4 * 4;
    int b = (int)(e >> 21);
    int c = (int)(e & 511);
    float4 xv = *(const float4*)(x + e);
    float vals[4] = {xv.x, xv.y, xv.z, xv.w};
    ushort_t o[4];
#pragma unroll
    for (int j = 0; j < 4; ++j) {
        int cc = c + j;
        float g  = s[b * 1024 + cc];
        float be = s[b * 1024 + 512 + cc];
        float mn = mean[b * 512 + cc];
        float rs = rstd[b * 512 + cc];
        o[j] = f2bf(g * (vals[j] - mn) * rs + be);
    }
    ull_t packed = (ull_t)o[0] |
        ((ull_t)o[1] << 16) | ((ull_t)o[2] << 32) | ((ull_t)o[3] << 48);
    *(ull_t*)(xn + e) = packed;
}

// ---------------------------------------------------------------------------
// GEMM 256x256 tile, BK=64, 8 waves (2Mx4N), persistent blocks.
// ROUND 7: B direct-from-global into registers (L2-resident weights),
// double-buffered in regs with one-K-tile prefetch (issued q1, used t+1).
// LDS holds A only (64 KB dbuf). Per phase: 4 ds_read_b128 (even), q0 issues
// the 4 A-stage loads for t+1, q3 ends with vmcnt(0) (all loads >=2 phases
// old -> near-free) before the publishing barrier (per-wave drain rule).
// EPI: 0 = bf16, 1 = +resid -> f32 + col stats atomics, 2 = gelu bf16, 3 = f32 +=
// ---------------------------------------------------------------------------
template<int EPI>
__global__ __launch_bounds__(512, 2) void gemm256(
        const ushort_t* __restrict__ A, const ushort_t* __restrict__ Bw,
        const float* __restrict__ bias, const float* __restrict__ resid,
        float* __restrict__ outf, ushort_t* __restrict__ outh,
        float* __restrict__ psum2, float* __restrict__ psq2,
        int N, int K, int gridN, int ntiles, int lnt) {
    __shared__ ushort_t lds[32768];   // 64 KiB: A dbuf [2][2 half][128][64]
    const int tid  = threadIdx.x;
    const int lane = tid & 63;
    const int wave = tid >> 6;
    const int wm = wave >> 2, wn = wave & 3;
    const int lm = lane & 15;
    const int kg = lane >> 4;
    const int nt = 1 << lnt;
    const int tpb = ntiles >> 8;

    const int orig = blockIdx.x;               // grid fixed at 256
    const int wgid = (orig & 7) * 32 + (orig >> 3);   // XCD swizzle

    // A ds_read byte addresses (slot-0 state); XOR swizzle folded in
    unsigned int lo0 = lm * 128 + ((kg * 16) ^ ((lm & 7) << 4));
    unsigned int vA0 = wm * 16384 + lo0;
    unsigned int vA1 = vA0 ^ 64;
    const char* ldsc = (const char*)lds;

    // A staging per-thread element offsets
    int offA[2][2];
#pragma unroll
    for (int rnd = 0; rnd < 2; ++rnd) {
        int chunk = tid + rnd * 512;
        int row = chunk >> 3;
        int g = chunk & 7;
        int gsw = g ^ (row & 7);
#pragma unroll
        for (int h = 0; h < 2; ++h)
            offA[h][rnd] = (h * 128 + row) * K + gsw * 8;
    }

    // B fragment per-thread row offsets (global, elements)
    long rowB[4];
#pragma unroll
    for (int n = 0; n < 4; ++n)
        rowB[n] = (long)(wn * 64 + n * 16 + lm) * K + kg * 8;

    f32x4 acc[8][4];
#pragma unroll
    for (int m = 0; m < 8; ++m)
#pragma unroll
        for (int n = 0; n < 4; ++n)
#pragma unroll
            for (int r = 0; r < 4; ++r) acc[m][n][r] = 0.f;

    // stage A both halves for K-step tt (4 x async 16B per thread)
    auto stageA = [&](long bcur, long bnxt, int dslot, int tt) {
        long mb = (tt < nt) ? bcur : bnxt;
        int kt = tt & (nt - 1);
        const ushort_t* base = A + mb + (kt << 6);
        ushort_t* dst = (ushort_t*)lds + dslot * 16384 + tid * 8;
        async_cp16(base + offA[0][0], dst);
        async_cp16(base + offA[0][1], dst + 4096);
        async_cp16(base + offA[1][0], dst + 8192);
        async_cp16(base + offA[1][1], dst + 12288);
    };

    short8 bX[4][2], bY[4][2];

    // first tile coords
    int tcur = wgid;
    int bm = tcur / gridN, bn = tcur - bm * gridN;
    long Am = (long)bm * 256 * K;
    long Bn = (long)bn * 256 * K;
    long Am2 = Am, Bn2 = Bn;

    // prologue: A(0) -> slot0; B(0) -> bX; drain; publish
    stageA(Am, Am, 0, 0);
    {
        const ushort_t* bp = Bw + Bn;
#pragma unroll
        for (int n = 0; n < 4; ++n) {
            bX[n][0] = *(const short8*)(bp + rowB[n]);
            bX[n][1] = *(const short8*)(bp + rowB[n] + 32);
        }
    }
    asm volatile("s_waitcnt vmcnt(0)" ::: "memory");
    __builtin_amdgcn_sched_barrier(0);
    __builtin_amdgcn_s_barrier();

    // one K-tile: 4 phases; bnow consumed, bnext prefetched (for t+1)
    auto ktile = [&](int t, short8 (&bnow)[4][2], short8 (&bnext)[4][2]) {
        const int c = t & 1;
        const int tt1 = t + 1;
        const long Bb = (tt1 < nt) ? Bn : Bn2;
        const int kt1 = tt1 & (nt - 1);
#pragma unroll
        for (int q = 0; q < 4; ++q) {
            short8 af[2][2];
#pragma unroll
            for (int mq = 0; mq < 2; ++mq) {
                af[mq][0] = *(const short8*)(ldsc + vA0 + (q * 4096 + mq * 2048));
                af[mq][1] = *(const short8*)(ldsc + vA1 + (q * 4096 + mq * 2048));
            }
            if (q == 0) stageA(Am, Am2, c ^ 1, tt1);
            if (q == 1) {
                const ushort_t* bp = Bw + Bb + (kt1 << 6);
#pragma unroll
                for (int n = 0; n < 4; ++n) {
                    bnext[n][0] = *(const short8*)(bp + rowB[n]);
                    bnext[n][1] = *(const short8*)(bp + rowB[n] + 32);
                }
            }
            __builtin_amdgcn_s_barrier();
            asm volatile("s_waitcnt lgkmcnt(0)" ::: "memory");
            __builtin_amdgcn_sched_barrier(0);
            __builtin_amdgcn_s_setprio(1);
#pragma unroll
            for (int mq = 0; mq < 2; ++mq)
#pragma unroll
                for (int n = 0; n < 4; ++n)
#pragma unroll
                    for (int ks = 0; ks < 2; ++ks)
                        acc[q * 2 + mq][n] = __builtin_amdgcn_mfma_f32_16x16x32_bf16(
                            af[mq][ks], bnow[n][ks], acc[q * 2 + mq][n], 0, 0, 0);
            __builtin_amdgcn_s_setprio(0);
            if (q == 3) {
                // all outstanding loads are >=2 phases old -> near-free drain;
                // own loads drained BEFORE the publishing barrier (per-wave rule)
                asm volatile("s_waitcnt vmcnt(0)" ::: "memory");
                __builtin_amdgcn_sched_barrier(0);
            }
            __builtin_amdgcn_s_barrier();
        }
        vA0 ^= 32768u; vA1 ^= 32768u;
    };

    for (int ti = 0; ti < tpb; ++ti) {
        int tnxt = (ti + 1 < tpb) ? tcur + 256 : tcur;
        int bm2 = tnxt / gridN, bn2 = tnxt - bm2 * gridN;
        Am2 = (long)bm2 * 256 * K;
        Bn2 = (long)bn2 * 256 * K;

        for (int t2 = 0; t2 < nt; t2 += 2) {
            ktile(t2, bX, bY);
            ktile(t2 + 1, bY, bX);
        }

        // ---- epilogue: D row=(lane>>4)*4+r, col=lane&15 ----
        const long tile_m = (long)bm * 256;
        const long tile_n = (long)bn * 256;
        float csum[4], csq[4];
        if (EPI == 1) {
#pragma unroll
            for (int n = 0; n < 4; ++n) { csum[n] = 0.f; csq[n] = 0.f; }
        }
#pragma unroll
        for (int m = 0; m < 8; ++m) {
            long row0 = tile_m + wm * 128 + m * 16 + kg * 4;
#pragma unroll
            for (int n = 0; n < 4; ++n) {
                long col = tile_n + wn * 64 + n * 16 + lm;
                float bb = bias[col];
#pragma unroll
                for (int r = 0; r < 4; ++r) {
                    long o = (row0 + r) * (long)N + col;
                    float v = acc[m][n][r] + bb;
                    if (EPI == 0) {
                        outh[o] = f2bf(v);
                    } else if (EPI == 1) {
                        float w = v + resid[o];
                        outf[o] = w;
                        csum[n] += w; csq[n] += w * w;
                    } else if (EPI == 2) {
                        outh[o] = f2bf(fast_gelu(v));
                    } else {
                        outf[o] += v;
                    }
                    acc[m][n][r] = 0.f;
                }
            }
        }
        if (EPI == 1) {
            int b = (int)(tile_m >> 12);
#pragma unroll
            for (int n = 0; n < 4; ++n) {
                int col = (int)(tile_n + wn * 64 + n * 16 + lm);
                atomicAdd(&psum2[b * 512 + col], csum[n]);
                atomicAdd(&psq2 [b * 512 + col], csq[n]);
            }
        }

        tcur = tnxt; bm = bm2; bn = bn2; Am = Am2; Bn = Bn2;
    }
}

// ---------------------------------------------------------------------------
// MFMA window attention: one wave per (branch, b, window, head) job.
// ---------------------------------------------------------------------------
__global__ __launch_bounds__(256) void attn_mfma(const ushort_t* __restrict__ qkv,
        const float* __restrict__ tbl0, const float* __restrict__ tbl1,
        ushort_t* __restrict__ attno) {
    __shared__ ushort_t lds[27648];   // 4 waves x (Vt [32][72] + P [64][72])
    const int tid = threadIdx.x;
    const int lane = tid & 63;
    const int wave = tid >> 6;
    const int job = blockIdx.x * 4 + wave;     // 8192 jobs
    const int branch = job >> 12;
    const int w_idx  = (job >> 3) & 511;
    const int head   = job & 7;
    const int b = w_idx >> 6, win = w_idx & 63;
    const int wh = win >> 3, ww = win & 7;
    const int c0 = branch * 256 + head * 32;
    const int i_lo = lane & 15;
    const int kg = lane >> 4;

    ushort_t* Vt = lds + wave * 6912;          // [32][72] bf16
    ushort_t* P  = lds + wave * 6912 + 2304;   // [64][72] bf16

    auto tokof = [&](int p) {
        int hh = wh * 8 + (p >> 3), wp = ww * 8 + (p & 7);
        if (branch) { hh = (hh + 4) & 63; wp = (wp + 4) & 63; }
        return b * 4096 + hh * 64 + wp;
    };

    // stage V transposed
    {
        const ushort_t* vp = qkv + (size_t)tokof(lane) * 1536 + 1024 + c0;
        short8 v0 = *(const short8*)(vp);
        short8 v1 = *(const short8*)(vp + 8);
        short8 v2 = *(const short8*)(vp + 16);
        short8 v3 = *(const short8*)(vp + 24);
#pragma unroll
        for (int e = 0; e < 8; ++e) {
            Vt[(e     ) * 72 + lane] = (ushort_t)v0[e];
            Vt[(e +  8) * 72 + lane] = (ushort_t)v1[e];
            Vt[(e + 16) * 72 + lane] = (ushort_t)v2[e];
            Vt[(e + 24) * 72 + lane] = (ushort_t)v3[e];
        }
    }

    short8 kf[4], qf[4];
#pragma unroll
    for (int m = 0; m < 4; ++m) {
        size_t rowb = (size_t)tokof(m * 16 + i_lo) * 1536;
        kf[m] = *(const short8*)(qkv + rowb + 512 + c0 + kg * 8);
        qf[m] = *(const short8*)(qkv + rowb + c0 + kg * 8);
    }

    f32x4 s[4][4];   // [mj][ni]
#pragma unroll
    for (int mj = 0; mj < 4; ++mj)
#pragma unroll
        for (int ni = 0; ni < 4; ++ni)
#pragma unroll
            for (int r = 0; r < 4; ++r) s[mj][ni][r] = 0.f;
#pragma unroll
    for (int mj = 0; mj < 4; ++mj)
#pragma unroll
        for (int ni = 0; ni < 4; ++ni)
            s[mj][ni] = __builtin_amdgcn_mfma_f32_16x16x32_bf16(kf[mj], qf[ni], s[mj][ni], 0, 0, 0);

    const float* tb;
    if (branch == 0) {
        tb = tbl0 + head * 4096;
    } else {
        int cls = ((wh == 7) ? 2 : 0) | ((ww == 7) ? 1 : 0);
        tb = tbl1 + (head * 4 + cls) * 4096;
    }
#pragma unroll
    for (int ni = 0; ni < 4; ++ni) {
        int i = ni * 16 + i_lo;
#pragma unroll
        for (int mj = 0; mj < 4; ++mj) {
            float4 bv = *(const float4*)(tb + i * 64 + mj * 16 + kg * 4);
            s[mj][ni][0] = s[mj][ni][0] * 0.17677669529663687f + bv.x;
            s[mj][ni][1] = s[mj][ni][1] * 0.17677669529663687f + bv.y;
            s[mj][ni][2] = s[mj][ni][2] * 0.17677669529663687f + bv.z;
            s[mj][ni][3] = s[mj][ni][3] * 0.17677669529663687f + bv.w;
        }
    }

    float mx[4], rs[4];
#pragma unroll
    for (int ni = 0; ni < 4; ++ni) {
        float m = -1e30f;
#pragma unroll
        for (int mj = 0; mj < 4; ++mj)
#pragma unroll
            for (int r = 0; r < 4; ++r) m = fmaxf(m, s[mj][ni][r]);
        m = fmaxf(m, __shfl_xor(m, 16));
        m = fmaxf(m, __shfl_xor(m, 32));
        mx[ni] = m;
    }
#pragma unroll
    for (int ni = 0; ni < 4; ++ni) {
        float sum = 0.f;
#pragma unroll
        for (int mj = 0; mj < 4; ++mj)
#pragma unroll
            for (int r = 0; r < 4; ++r) {
                float e = __expf(s[mj][ni][r] - mx[ni]);
                s[mj][ni][r] = e;
                sum += e;
            }
        sum += __shfl_xor(sum, 16);
        sum += __shfl_xor(sum, 32);
        rs[ni] = sum;
    }

#pragma unroll
    for (int ni = 0; ni < 4; ++ni) {
        int i = ni * 16 + i_lo;
#pragma unroll
        for (int mj = 0; mj < 4; ++mj) {
            unsigned w0 = cvt_pk_bf16(s[mj][ni][0], s[mj][ni][1]);
            unsigned w1 = cvt_pk_bf16(s[mj][ni][2], s[mj][ni][3]);
            ull_t w = (ull_t)w0 | ((ull_t)w1 << 32);
            *(ull_t*)&P[i * 72 + mj * 16 + kg * 4] = w;
        }
    }
    asm volatile("s_waitcnt lgkmcnt(0)" ::: "memory");
    __builtin_amdgcn_sched_barrier(0);

    short8 va[2][2];
    short8 pb[4][2];
#pragma unroll
    for (int md = 0; md < 2; ++md)
#pragma unroll
        for (int ks = 0; ks < 2; ++ks)
            va[md][ks] = *(const short8*)&Vt[(md * 16 + i_lo) * 72 + ks * 32 + kg * 8];
#pragma unroll
    for (int ni = 0; ni < 4; ++ni)
#pragma unroll
        for (int ks = 0; ks < 2; ++ks)
            pb[ni][ks] = *(const short8*)&P[(ni * 16 + i_lo) * 72 + ks * 32 + kg * 8];

    f32x4 o[2][4];
#pragma unroll
    for (int md = 0; md < 2; ++md)
#pragma unroll
        for (int ni = 0; ni < 4; ++ni)
#pragma unroll
            for (int r = 0; r < 4; ++r) o[md][ni][r] = 0.f;
#pragma unroll
    for (int md = 0; md < 2; ++md)
#pragma unroll
        for (int ni = 0; ni < 4; ++ni)
#pragma unroll
            for (int ks = 0; ks < 2; ++ks)
                o[md][ni] = __builtin_amdgcn_mfma_f32_16x16x32_bf16(va[md][ks], pb[ni][ks], o[md][ni], 0, 0, 0);

#pragma unroll
    for (int ni = 0; ni < 4; ++ni) {
        float inv = 1.f / rs[ni];
        ushort_t* op = attno + (size_t)tokof(ni * 16 + i_lo) * 512 + c0;
#pragma unroll
        for (int md = 0; md < 2; ++md) {
            ushort_t h0 = f2bf(o[md][ni][0] * inv);
            ushort_t h1 = f2bf(o[md][ni][1] * inv);
            ushort_t h2 = f2bf(o[md][ni][2] * inv);
            ushort_t h3 = f2bf(o[md][ni][3] * inv);
            ull_t w = (ull_t)h0 | ((ull_t)h1 << 16) | ((ull_t)h2 << 32) | ((ull_t)h3 << 48);
            *(ull_t*)(op + md * 16 + kg * 4) = w;
        }
    }
}

// ---------------------------------------------------------------------------
extern "C" void kernel_launch(void* const* d_in, const int* in_sizes, int n_in,
                              void* d_out, int out_size, void* d_ws, size_t ws_size,
                              hipStream_t stream) {
    const float* x      = (const float*)d_in[0];
    const float* style  = (const float*)d_in[1];
    const float* ada1_w = (const float*)d_in[2];
    const float* ada1_b = (const float*)d_in[3];
    const float* qkv_w  = (const float*)d_in[4];
    const float* qkv_b  = (const float*)d_in[5];
    const float* rpb1   = (const float*)d_in[6];
    const float* rpb2   = (const float*)d_in[7];
    const float* proj_w = (const float*)d_in[8];
    const float* proj_b = (const float*)d_in[9];
    const float* ada2_w = (const float*)d_in[10];
    const float* ada2_b = (const float*)d_in[11];
    const float* mlp_w1 = (const float*)d_in[12];
    const float* mlp_b1 = (const float*)d_in[13];
    const float* mlp_w2 = (const float*)d_in[14];
    const float* mlp_b2 = (const float*)d_in[15];
    float* outf = (float*)d_out;

    char* W = (char*)d_ws;
    ushort_t* qkvb    = (ushort_t*)(W);                      // 96 MB (32768 x 1536)
    ushort_t* attno   = (ushort_t*)(W + 100663296);          // 32 MB (32768 x 512)
    ushort_t* hbuf    = (ushort_t*)(W);                      // 128 MB overlay (32768 x 2048)
    ushort_t* xn      = (ushort_t*)(W + 134217728);          // 32 MB (32768 x 512)
    ushort_t* qkv_wb  = (ushort_t*)(W + 167772160);
    ushort_t* proj_wb = (ushort_t*)(W + 167772160 + 1572864);
    ushort_t* w1b     = (ushort_t*)(W + 167772160 + 2097152);
    ushort_t* w2b     = (ushort_t*)(W + 167772160 + 4194304);
    float* freg  = (float*)(W + 167772160 + 6291456);
    float* s1    = freg;
    float* s2    = freg + 8192;
    float* mean1 = freg + 16384;
    float* rstd1 = freg + 20480;
    float* mean2 = freg + 24576;
    float* rstd2 = freg + 28672;
    float* psum  = freg + 32768;    // 8*32*512
    float* psq   = freg + 163840;   // 8*32*512
    float* psum2 = freg + 294912;   // 8*512
    float* psq2  = freg + 303104;   // 8*512
    float* tbl0  = freg + 311296;   // 8*64*64
    float* tbl1  = freg + 344064;   // 8*4*64*64

    conv_zero<<<12960, 256, 0, stream>>>(qkv_w, qkv_wb, proj_w, proj_wb,
                                         mlp_w1, w1b, mlp_w2, w2b, psum2, psq2,
                                         rpb1, rpb2, tbl0, tbl1);

    style_kernel<<<64, 256, 0, stream>>>(style, ada1_w, ada1_b, ada2_w, ada2_b, s1, s2);

    stats_part<<<256, 512, 0, stream>>>(x, psum, psq);
    stats_fin<<<16, 256, 0, stream>>>(psum, psq, mean1, rstd1);
    adain_kernel<<<16384, 256, 0, stream>>>(x, s1, mean1, rstd1, xn);

    // qkv: 768 tiles, gridN=6
    gemm256<0><<<256, 512, 0, stream>>>(xn, qkv_wb, qkv_b, nullptr, nullptr, qkvb,
                                        nullptr, nullptr, 1536, 512, 6, 768, 3);

    attn_mfma<<<2048, 256, 0, stream>>>(qkvb, tbl0, tbl1, attno);

    // proj + residual -> d_out (f32) + fused adain2 stats
    gemm256<1><<<256, 512, 0, stream>>>(attno, proj_wb, proj_b, x, outf, nullptr,
                                        psum2, psq2, 512, 512, 2, 256, 3);

    stats_fin2<<<16, 256, 0, stream>>>(psum2, psq2, mean2, rstd2);
    adain_kernel<<<16384, 256, 0, stream>>>(outf, s2, mean2, rstd2, xn);

    // mlp1: 1024 tiles, gridN=8
    gemm256<2><<<256, 512, 0, stream>>>(xn, w1b, mlp_b1, nullptr, nullptr, hbuf,
                                        nullptr, nullptr, 2048, 512, 8, 1024, 3);
    // mlp2: 256 tiles, gridN=2, K=2048 (nt=32)
    gemm256<3><<<256, 512, 0, stream>>>(hbuf, w2b, mlp_b2, nullptr, outf, nullptr,
                                        nullptr, nullptr, 512, 2048, 2, 256, 5);
}

// Round 8
// 416.531 us; speedup vs baseline: 1.3860x; 1.3860x over previous
//
#include <hip/hip_runtime.h>
#include <math.h>

typedef __attribute__((ext_vector_type(8))) short short8;
typedef __attribute__((ext_vector_type(4))) float f32x4;
typedef unsigned short ushort_t;
typedef unsigned long long ull_t;

__device__ __forceinline__ float bf2f(ushort_t u) {
    return __uint_as_float(((unsigned int)u) << 16);
}
__device__ __forceinline__ ushort_t f2bf(float f) {
    unsigned int u = __float_as_uint(f);
    unsigned int r = u + 0x7fffu + ((u >> 16) & 1u);   // RTN-even
    return (ushort_t)(r >> 16);
}
__device__ __forceinline__ unsigned cvt_pk_bf16(float lo, float hi) {
    unsigned r;
    asm volatile("v_cvt_pk_bf16_f32 %0, %1, %2" : "=v"(r) : "v"(lo), "v"(hi));
    return r;
}

__device__ __forceinline__ void async_cp16(const void* g, void* l) {
    __builtin_amdgcn_global_load_lds((const __attribute__((address_space(1))) void*)g,
                                     (__attribute__((address_space(3))) void*)l, 16, 0, 0);
}

// tanh-form gelu via hardware exp: max abs err ~3e-4*|x|
__device__ __forceinline__ float fast_gelu(float v) {
    float u2 = 2.0f * v * (0.7978845608028654f + 0.0356774081f * v * v);
    float e = __expf(u2);
    float r = 1.0f / (e + 1.0f);
    return v - v * r;
}

// ---------------------------------------------------------------------------
// fused setup: 4 weight conversions + zero psum2/psq2 + expanded bias tables
// ---------------------------------------------------------------------------
__global__ __launch_bounds__(256) void conv_zero(
        const float* __restrict__ qkv_w, ushort_t* __restrict__ qkv_wb,
        const float* __restrict__ proj_w, ushort_t* __restrict__ proj_wb,
        const float* __restrict__ w1, ushort_t* __restrict__ w1b,
        const float* __restrict__ w2, ushort_t* __restrict__ w2b,
        float* __restrict__ psum2, float* __restrict__ psq2,
        const float* __restrict__ rpb1, const float* __restrict__ rpb2,
        float* __restrict__ tbl0, float* __restrict__ tbl1) {
    int i = blockIdx.x * 256 + threadIdx.x;
    if (i < 786432) {
        qkv_wb[i] = f2bf(qkv_w[i]);
    } else if (i < 1048576) {
        int j = i - 786432; proj_wb[j] = f2bf(proj_w[j]);
    } else if (i < 2097152) {
        int j = i - 1048576; w1b[j] = f2bf(w1[j]);
    } else if (i < 3145728) {
        int j = i - 2097152; w2b[j] = f2bf(w2[j]);
    } else if (i < 3153920) {
        int j = i - 3145728;       // [0, 8192)
        psum2[j] = 0.f; psq2[j] = 0.f;
    } else {
        int t = i - 3153920;       // [0, 163840)
        if (t < 32768) {
            int h = t >> 12, ij = t & 4095;
            int qi = ij >> 6, kj = ij & 63;
            int idx = ((qi >> 3) - (kj >> 3)) + ((qi & 7) - (kj & 7)) + 29;
            tbl0[t] = rpb1[idx * 8 + h];
        } else {
            int u = t - 32768;     // [0, 131072)
            int ij = u & 4095;
            int cls = (u >> 12) & 3;
            int h = u >> 14;
            int qi = ij >> 6, kj = ij & 63;
            int idx = ((qi >> 3) - (kj >> 3)) + ((qi & 7) - (kj & 7)) + 29;
            float v = rpb2[idx * 8 + h];
            int gh_i = (cls & 2) ? (((qi >> 3) < 4) ? 1 : 2) : 0;
            int gw_i = (cls & 1) ? (((qi & 7) < 4) ? 1 : 2) : 0;
            int gh_j = (cls & 2) ? (((kj >> 3) < 4) ? 1 : 2) : 0;
            int gw_j = (cls & 1) ? (((kj & 7) < 4) ? 1 : 2) : 0;
            if (gh_i * 3 + gw_i != gh_j * 3 + gw_j) v -= 100.f;
            tbl1[u] = v;
        }
    }
}

// ---------------------------------------------------------------------------
// style modulation
// ---------------------------------------------------------------------------
__global__ __launch_bounds__(256) void style_kernel(const float* __restrict__ style,
        const float* __restrict__ w1, const float* __restrict__ b1,
        const float* __restrict__ w2, const float* __restrict__ b2,
        float* __restrict__ s1, float* __restrict__ s2) {
    int t = blockIdx.x * 256 + threadIdx.x;
    int which = t >> 13;
    int idx = t & 8191;
    int b = idx >> 10, j = idx & 1023;
    const float* w = which ? w2 : w1;
    const float* bb = which ? b2 : b1;
    const float* st = style + b * 512;
    const float* wr = w + (size_t)j * 512;
    float acc = 0.f;
    for (int k = 0; k < 512; ++k) acc += st[k] * wr[k];
    float v = acc * 0.04419417382415922f + bb[j];
    (which ? s2 : s1)[idx] = v;
}

// ---------------------------------------------------------------------------
// instance-norm stats (adain1 path)
// ---------------------------------------------------------------------------
__global__ __launch_bounds__(512) void stats_part(const float* __restrict__ x,
        float* __restrict__ psum, float* __restrict__ psq) {
    int b = blockIdx.x >> 5;
    int ch = blockIdx.x & 31;
    int c = threadIdx.x;
    const float* p = x + ((size_t)b * 4096 + (size_t)ch * 128) * 512 + c;
    float s = 0.f, q = 0.f;
    for (int t = 0; t < 128; ++t) {
        float v = p[(size_t)t * 512];
        s += v; q += v * v;
    }
    psum[(size_t)blockIdx.x * 512 + c] = s;
    psq [(size_t)blockIdx.x * 512 + c] = q;
}

__global__ __launch_bounds__(256) void stats_fin(const float* __restrict__ psum,
        const float* __restrict__ psq, float* __restrict__ mean, float* __restrict__ rstd) {
    int i = blockIdx.x * 256 + threadIdx.x;
    int b = i >> 9, c = i & 511;
    float s = 0.f, q = 0.f;
    for (int ch = 0; ch < 32; ++ch) {
        s += psum[(size_t)(b * 32 + ch) * 512 + c];
        q += psq [(size_t)(b * 32 + ch) * 512 + c];
    }
    float m = s * (1.f / 4096.f);
    float v = q * (1.f / 4096.f) - m * m;
    mean[i] = m;
    rstd[i] = rsqrtf(v + 1e-5f);
}

__global__ __launch_bounds__(256) void stats_fin2(const float* __restrict__ psum2,
        const float* __restrict__ psq2, float* __restrict__ mean, float* __restrict__ rstd) {
    int i = blockIdx.x * 256 + threadIdx.x;   // 4096
    float m = psum2[i] * (1.f / 4096.f);
    float v = psq2[i] * (1.f / 4096.f) - m * m;
    mean[i] = m;
    rstd[i] = rsqrtf(v + 1e-5f);
}

// ---------------------------------------------------------------------------
// adain apply
// ---------------------------------------------------------------------------
__global__ __launch_bounds__(256) void adain_kernel(const float* __restrict__ x,
        const float* __restrict__ s, const float* __restrict__ mean,
        const float* __restrict__ rstd, ushort_t* __restrict__ xn) {
    size_t i4 = (size_t)blockIdx.x * 256 + threadIdx.x;
    size_t e = i4 * 4;
    int b = (int)(e >> 21);
    int c = (int)(e & 511);
    float4 xv = *(const float4*)(x + e);
    float vals[4] = {xv.x, xv.y, xv.z, xv.w};
    ushort_t o[4];
#pragma unroll
    for (int j = 0; j < 4; ++j) {
        int cc = c + j;
        float g  = s[b * 1024 + cc];
        float be = s[b * 1024 + 512 + cc];
        float mn = mean[b * 512 + cc];
        float rs = rstd[b * 512 + cc];
        o[j] = f2bf(g * (vals[j] - mn) * rs + be);
    }
    ull_t packed = (ull_t)o[0] |
        ((ull_t)o[1] << 16) | ((ull_t)o[2] << 32) | ((ull_t)o[3] << 48);
    *(ull_t*)(xn + e) = packed;
}

// ---------------------------------------------------------------------------
// GEMM 256x256 tile, BK=64, 8 waves (2Mx4N), persistent blocks (grid=256).
// ROUND 8: B back in LDS (round-6 structure) but SINGLE barrier per phase:
//   {ds_read; stage-issue; setprio(1); MFMA (compiler fine-grained lgkmcnt);
//    setprio(0); [q3: vmcnt(4) own-drain]; s_barrier}
// Safety: a wave's reads of region R complete before its MFMA (data deps)
// and hence before the phase-end barrier; all writes into R are issued >=1
// phase later -> read-before-overwrite holds with one barrier. q3 vmcnt(4)
// before the publishing barrier drains A(t+1),B(t+1), leaves B(t+2) in
// flight (counted, never 0). Mid-phase barrier removal lets one wave's MFMA
// overlap the other wave's ds_read on the same SIMD.
// EPI: 0 = bf16, 1 = +resid -> f32 + col stats atomics, 2 = gelu bf16, 3 = f32 +=
// ---------------------------------------------------------------------------
template<int EPI>
__global__ __launch_bounds__(512, 2) void gemm256(
        const ushort_t* __restrict__ A, const ushort_t* __restrict__ Bw,
        const float* __restrict__ bias, const float* __restrict__ resid,
        float* __restrict__ outf, ushort_t* __restrict__ outh,
        float* __restrict__ psum2, float* __restrict__ psq2,
        int N, int K, int gridN, int ntiles, int lnt) {
    __shared__ ushort_t lds[65536];   // 128 KiB
    const int tid  = threadIdx.x;
    const int lane = tid & 63;
    const int wave = tid >> 6;
    const int wm = wave >> 2, wn = wave & 3;
    const int lm = lane & 15;
    const int kg = lane >> 4;
    const int nt = 1 << lnt;
    const int tpb = ntiles >> 8;

    const int orig = blockIdx.x;               // grid fixed at 256
    const int wgid = (orig & 7) * 32 + (orig >> 3);   // XCD swizzle

    unsigned int lo0 = lm * 128 + ((kg * 16) ^ ((lm & 7) << 4));
    unsigned int lo1 = lo0 ^ 64;
    unsigned int vA0 = wm * 16384 + lo0;
    unsigned int vA1 = wm * 16384 + lo1;
    unsigned int vB0 = 65536 + (wn >> 1) * 16384 + (wn & 1) * 8192 + lo0;
    unsigned int vB1 = 65536 + (wn >> 1) * 16384 + (wn & 1) * 8192 + lo1;
    const char* ldsc = (const char*)lds;

    int off[2][2];
#pragma unroll
    for (int rnd = 0; rnd < 2; ++rnd) {
        int chunk = tid + rnd * 512;
        int row = chunk >> 3;
        int g = chunk & 7;
        int gsw = g ^ (row & 7);
#pragma unroll
        for (int h = 0; h < 2; ++h)
            off[h][rnd] = (h * 128 + row) * K + gsw * 8;
    }

    f32x4 acc[8][4];
#pragma unroll
    for (int m = 0; m < 8; ++m)
#pragma unroll
        for (int n = 0; n < 4; ++n)
#pragma unroll
            for (int r = 0; r < 4; ++r) acc[m][n][r] = 0.f;

    auto stage = [&](const ushort_t* __restrict__ mat, long bcur, long bnxt,
                     int dslot, int h, int tt, int isB) {
        long mb = (tt < nt) ? bcur : bnxt;
        int kt = tt & (nt - 1);
        const ushort_t* base = mat + mb + (kt << 6);
        ushort_t* dst = (ushort_t*)lds + isB * 32768 + dslot * 16384 + h * 8192 + tid * 8;
#pragma unroll
        for (int rnd = 0; rnd < 2; ++rnd)
            async_cp16(base + off[h][rnd], dst + rnd * 4096);
    };

    int tcur = wgid;
    int bm = tcur / gridN, bn = tcur - bm * gridN;
    long Am = (long)bm * 256 * K;
    long Bn = (long)bn * 256 * K;

    stage(A,  Am, Am, 0, 0, 0, 0); stage(A,  Am, Am, 0, 1, 0, 0);
    stage(Bw, Bn, Bn, 0, 0, 0, 1); stage(Bw, Bn, Bn, 0, 1, 0, 1);
    stage(Bw, Bn, Bn, 1, 0, 1, 1); stage(Bw, Bn, Bn, 1, 1, 1, 1);
    asm volatile("s_waitcnt vmcnt(4)" ::: "memory");
    __builtin_amdgcn_sched_barrier(0);
    __builtin_amdgcn_s_barrier();
    asm volatile("" ::: "memory");

    for (int ti = 0; ti < tpb; ++ti) {
        int tnxt = (ti + 1 < tpb) ? tcur + 256 : tcur;
        int bm2 = tnxt / gridN, bn2 = tnxt - bm2 * gridN;
        long Am2 = (long)bm2 * 256 * K;
        long Bn2 = (long)bn2 * 256 * K;

#pragma unroll 2
        for (int t = 0; t < nt; ++t) {
            const int c = t & 1;
            short8 bfr[4][2];
#pragma unroll
            for (int q = 0; q < 4; ++q) {
                short8 af[2][2];
#pragma unroll
                for (int mq = 0; mq < 2; ++mq) {
                    af[mq][0] = *(const short8*)(ldsc + vA0 + (q * 4096 + mq * 2048));
                    af[mq][1] = *(const short8*)(ldsc + vA1 + (q * 4096 + mq * 2048));
                }
                if (q == 0) {
#pragma unroll
                    for (int n = 0; n < 4; ++n) {
                        bfr[n][0] = *(const short8*)(ldsc + vB0 + n * 2048);
                        bfr[n][1] = *(const short8*)(ldsc + vB1 + n * 2048);
                    }
                }
                if      (q == 0) stage(A,  Am, Am2, c ^ 1, 0, t + 1, 0);
                else if (q == 1) stage(A,  Am, Am2, c ^ 1, 1, t + 1, 0);
                else if (q == 2) stage(Bw, Bn, Bn2, c,     0, t + 2, 1);
                else             stage(Bw, Bn, Bn2, c,     1, t + 2, 1);

                // no mid-phase barrier, no forced lgkmcnt(0): compiler emits
                // fine-grained lgkmcnt for the af/bfr->MFMA deps; waves slide.
                __builtin_amdgcn_s_setprio(1);
#pragma unroll
                for (int mq = 0; mq < 2; ++mq)
#pragma unroll
                    for (int n = 0; n < 4; ++n)
#pragma unroll
                        for (int ks = 0; ks < 2; ++ks)
                            acc[q * 2 + mq][n] = __builtin_amdgcn_mfma_f32_16x16x32_bf16(
                                af[mq][ks], bfr[n][ks], acc[q * 2 + mq][n], 0, 0, 0);
                __builtin_amdgcn_s_setprio(0);
                if (q == 3) {
                    // own-drain BEFORE publishing barrier (per-wave rule):
                    // completes A(t+1),B(t+1); leaves B(t+2) in flight.
                    asm volatile("s_waitcnt vmcnt(4)" ::: "memory");
                    __builtin_amdgcn_sched_barrier(0);
                }
                __builtin_amdgcn_s_barrier();
                asm volatile("" ::: "memory");
            }
            vA0 ^= 32768u; vA1 ^= 32768u; vB0 ^= 32768u; vB1 ^= 32768u;
        }

        // ---- epilogue: D row=(lane>>4)*4+r, col=lane&15 ----
        const long tile_m = (long)bm * 256;
        const long tile_n = (long)bn * 256;
        float csum[4], csq[4];
        if (EPI == 1) {
#pragma unroll
            for (int n = 0; n < 4; ++n) { csum[n] = 0.f; csq[n] = 0.f; }
        }
#pragma unroll
        for (int m = 0; m < 8; ++m) {
            long row0 = tile_m + wm * 128 + m * 16 + kg * 4;
#pragma unroll
            for (int n = 0; n < 4; ++n) {
                long col = tile_n + wn * 64 + n * 16 + lm;
                float bb = bias[col];
#pragma unroll
                for (int r = 0; r < 4; ++r) {
                    long o = (row0 + r) * (long)N + col;
                    float v = acc[m][n][r] + bb;
                    if (EPI == 0) {
                        outh[o] = f2bf(v);
                    } else if (EPI == 1) {
                        float w = v + resid[o];
                        outf[o] = w;
                        csum[n] += w; csq[n] += w * w;
                    } else if (EPI == 2) {
                        outh[o] = f2bf(fast_gelu(v));
                    } else {
                        outf[o] += v;
                    }
                    acc[m][n][r] = 0.f;
                }
            }
        }
        if (EPI == 1) {
            int b = (int)(tile_m >> 12);
#pragma unroll
            for (int n = 0; n < 4; ++n) {
                int col = (int)(tile_n + wn * 64 + n * 16 + lm);
                atomicAdd(&psum2[b * 512 + col], csum[n]);
                atomicAdd(&psq2 [b * 512 + col], csq[n]);
            }
        }

        tcur = tnxt; bm = bm2; bn = bn2; Am = Am2; Bn = Bn2;
    }
}

// ---------------------------------------------------------------------------
// MFMA window attention: one wave per (branch, b, window, head) job.
// ---------------------------------------------------------------------------
__global__ __launch_bounds__(256) void attn_mfma(const ushort_t* __restrict__ qkv,
        const float* __restrict__ tbl0, const float* __restrict__ tbl1,
        ushort_t* __restrict__ attno) {
    __shared__ ushort_t lds[27648];   // 4 waves x (Vt [32][72] + P [64][72])
    const int tid = threadIdx.x;
    const int lane = tid & 63;
    const int wave = tid >> 6;
    const int job = blockIdx.x * 4 + wave;     // 8192 jobs
    const int branch = job >> 12;
    const int w_idx  = (job >> 3) & 511;
    const int head   = job & 7;
    const int b = w_idx >> 6, win = w_idx & 63;
    const int wh = win >> 3, ww = win & 7;
    const int c0 = branch * 256 + head * 32;
    const int i_lo = lane & 15;
    const int kg = lane >> 4;

    ushort_t* Vt = lds + wave * 6912;          // [32][72] bf16
    ushort_t* P  = lds + wave * 6912 + 2304;   // [64][72] bf16

    auto tokof = [&](int p) {
        int hh = wh * 8 + (p >> 3), wp = ww * 8 + (p & 7);
        if (branch) { hh = (hh + 4) & 63; wp = (wp + 4) & 63; }
        return b * 4096 + hh * 64 + wp;
    };

    // stage V transposed
    {
        const ushort_t* vp = qkv + (size_t)tokof(lane) * 1536 + 1024 + c0;
        short8 v0 = *(const short8*)(vp);
        short8 v1 = *(const short8*)(vp + 8);
        short8 v2 = *(const short8*)(vp + 16);
        short8 v3 = *(const short8*)(vp + 24);
#pragma unroll
        for (int e = 0; e < 8; ++e) {
            Vt[(e     ) * 72 + lane] = (ushort_t)v0[e];
            Vt[(e +  8) * 72 + lane] = (ushort_t)v1[e];
            Vt[(e + 16) * 72 + lane] = (ushort_t)v2[e];
            Vt[(e + 24) * 72 + lane] = (ushort_t)v3[e];
        }
    }

    short8 kf[4], qf[4];
#pragma unroll
    for (int m = 0; m < 4; ++m) {
        size_t rowb = (size_t)tokof(m * 16 + i_lo) * 1536;
        kf[m] = *(const short8*)(qkv + rowb + 512 + c0 + kg * 8);
        qf[m] = *(const short8*)(qkv + rowb + c0 + kg * 8);
    }

    f32x4 s[4][4];   // [mj][ni]
#pragma unroll
    for (int mj = 0; mj < 4; ++mj)
#pragma unroll
        for (int ni = 0; ni < 4; ++ni)
#pragma unroll
            for (int r = 0; r < 4; ++r) s[mj][ni][r] = 0.f;
#pragma unroll
    for (int mj = 0; mj < 4; ++mj)
#pragma unroll
        for (int ni = 0; ni < 4; ++ni)
            s[mj][ni] = __builtin_amdgcn_mfma_f32_16x16x32_bf16(kf[mj], qf[ni], s[mj][ni], 0, 0, 0);

    const float* tb;
    if (branch == 0) {
        tb = tbl0 + head * 4096;
    } else {
        int cls = ((wh == 7) ? 2 : 0) | ((ww == 7) ? 1 : 0);
        tb = tbl1 + (head * 4 + cls) * 4096;
    }
#pragma unroll
    for (int ni = 0; ni < 4; ++ni) {
        int i = ni * 16 + i_lo;
#pragma unroll
        for (int mj = 0; mj < 4; ++mj) {
            float4 bv = *(const float4*)(tb + i * 64 + mj * 16 + kg * 4);
            s[mj][ni][0] = s[mj][ni][0] * 0.17677669529663687f + bv.x;
            s[mj][ni][1] = s[mj][ni][1] * 0.17677669529663687f + bv.y;
            s[mj][ni][2] = s[mj][ni][2] * 0.17677669529663687f + bv.z;
            s[mj][ni][3] = s[mj][ni][3] * 0.17677669529663687f + bv.w;
        }
    }

    float mx[4], rs[4];
#pragma unroll
    for (int ni = 0; ni < 4; ++ni) {
        float m = -1e30f;
#pragma unroll
        for (int mj = 0; mj < 4; ++mj)
#pragma unroll
            for (int r = 0; r < 4; ++r) m = fmaxf(m, s[mj][ni][r]);
        m = fmaxf(m, __shfl_xor(m, 16));
        m = fmaxf(m, __shfl_xor(m, 32));
        mx[ni] = m;
    }
#pragma unroll
    for (int ni = 0; ni < 4; ++ni) {
        float sum = 0.f;
#pragma unroll
        for (int mj = 0; mj < 4; ++mj)
#pragma unroll
            for (int r = 0; r < 4; ++r) {
                float e = __expf(s[mj][ni][r] - mx[ni]);
                s[mj][ni][r] = e;
                sum += e;
            }
        sum += __shfl_xor(sum, 16);
        sum += __shfl_xor(sum, 32);
        rs[ni] = sum;
    }

#pragma unroll
    for (int ni = 0; ni < 4; ++ni) {
        int i = ni * 16 + i_lo;
#pragma unroll
        for (int mj = 0; mj < 4; ++mj) {
            unsigned w0 = cvt_pk_bf16(s[mj][ni][0], s[mj][ni][1]);
            unsigned w1 = cvt_pk_bf16(s[mj][ni][2], s[mj][ni][3]);
            ull_t w = (ull_t)w0 | ((ull_t)w1 << 32);
            *(ull_t*)&P[i * 72 + mj * 16 + kg * 4] = w;
        }
    }
    asm volatile("s_waitcnt lgkmcnt(0)" ::: "memory");
    __builtin_amdgcn_sched_barrier(0);

    short8 va[2][2];
    short8 pb[4][2];
#pragma unroll
    for (int md = 0; md < 2; ++md)
#pragma unroll
        for (int ks = 0; ks < 2; ++ks)
            va[md][ks] = *(const short8*)&Vt[(md * 16 + i_lo) * 72 + ks * 32 + kg * 8];
#pragma unroll
    for (int ni = 0; ni < 4; ++ni)
#pragma unroll
        for (int ks = 0; ks < 2; ++ks)
            pb[ni][ks] = *(const short8*)&P[(ni * 16 + i_lo) * 72 + ks * 32 + kg * 8];

    f32x4 o[2][4];
#pragma unroll
    for (int md = 0; md < 2; ++md)
#pragma unroll
        for (int ni = 0; ni < 4; ++ni)
#pragma unroll
            for (int r = 0; r < 4; ++r) o[md][ni][r] = 0.f;
#pragma unroll
    for (int md = 0; md < 2; ++md)
#pragma unroll
        for (int ni = 0; ni < 4; ++ni)
#pragma unroll
            for (int ks = 0; ks < 2; ++ks)
                o[md][ni] = __builtin_amdgcn_mfma_f32_16x16x32_bf16(va[md][ks], pb[ni][ks], o[md][ni], 0, 0, 0);

#pragma unroll
    for (int ni = 0; ni < 4; ++ni) {
        float inv = 1.f / rs[ni];
        ushort_t* op = attno + (size_t)tokof(ni * 16 + i_lo) * 512 + c0;
#pragma unroll
        for (int md = 0; md < 2; ++md) {
            ushort_t h0 = f2bf(o[md][ni][0] * inv);
            ushort_t h1 = f2bf(o[md][ni][1] * inv);
            ushort_t h2 = f2bf(o[md][ni][2] * inv);
            ushort_t h3 = f2bf(o[md][ni][3] * inv);
            ull_t w = (ull_t)h0 | ((ull_t)h1 << 16) | ((ull_t)h2 << 32) | ((ull_t)h3 << 48);
            *(ull_t*)(op + md * 16 + kg * 4) = w;
        }
    }
}

// ---------------------------------------------------------------------------
extern "C" void kernel_launch(void* const* d_in, const int* in_sizes, int n_in,
                              void* d_out, int out_size, void* d_ws, size_t ws_size,
                              hipStream_t stream) {
    const float* x      = (const float*)d_in[0];
    const float* style  = (const float*)d_in[1];
    const float* ada1_w = (const float*)d_in[2];
    const float* ada1_b = (const float*)d_in[3];
    const float* qkv_w  = (const float*)d_in[4];
    const float* qkv_b  = (const float*)d_in[5];
    const float* rpb1   = (const float*)d_in[6];
    const float* rpb2   = (const float*)d_in[7];
    const float* proj_w = (const float*)d_in[8];
    const float* proj_b = (const float*)d_in[9];
    const float* ada2_w = (const float*)d_in[10];
    const float* ada2_b = (const float*)d_in[11];
    const float* mlp_w1 = (const float*)d_in[12];
    const float* mlp_b1 = (const float*)d_in[13];
    const float* mlp_w2 = (const float*)d_in[14];
    const float* mlp_b2 = (const float*)d_in[15];
    float* outf = (float*)d_out;

    char* W = (char*)d_ws;
    ushort_t* qkvb    = (ushort_t*)(W);                      // 96 MB (32768 x 1536)
    ushort_t* attno   = (ushort_t*)(W + 100663296);          // 32 MB (32768 x 512)
    ushort_t* hbuf    = (ushort_t*)(W);                      // 128 MB overlay (32768 x 2048)
    ushort_t* xn      = (ushort_t*)(W + 134217728);          // 32 MB (32768 x 512)
    ushort_t* qkv_wb  = (ushort_t*)(W + 167772160);
    ushort_t* proj_wb = (ushort_t*)(W + 167772160 + 1572864);
    ushort_t* w1b     = (ushort_t*)(W + 167772160 + 2097152);
    ushort_t* w2b     = (ushort_t*)(W + 167772160 + 4194304);
    float* freg  = (float*)(W + 167772160 + 6291456);
    float* s1    = freg;
    float* s2    = freg + 8192;
    float* mean1 = freg + 16384;
    float* rstd1 = freg + 20480;
    float* mean2 = freg + 24576;
    float* rstd2 = freg + 28672;
    float* psum  = freg + 32768;    // 8*32*512
    float* psq   = freg + 163840;   // 8*32*512
    float* psum2 = freg + 294912;   // 8*512
    float* psq2  = freg + 303104;   // 8*512
    float* tbl0  = freg + 311296;   // 8*64*64
    float* tbl1  = freg + 344064;   // 8*4*64*64

    conv_zero<<<12960, 256, 0, stream>>>(qkv_w, qkv_wb, proj_w, proj_wb,
                                         mlp_w1, w1b, mlp_w2, w2b, psum2, psq2,
                                         rpb1, rpb2, tbl0, tbl1);

    style_kernel<<<64, 256, 0, stream>>>(style, ada1_w, ada1_b, ada2_w, ada2_b, s1, s2);

    stats_part<<<256, 512, 0, stream>>>(x, psum, psq);
    stats_fin<<<16, 256, 0, stream>>>(psum, psq, mean1, rstd1);
    adain_kernel<<<16384, 256, 0, stream>>>(x, s1, mean1, rstd1, xn);

    // qkv: 768 tiles, gridN=6
    gemm256<0><<<256, 512, 0, stream>>>(xn, qkv_wb, qkv_b, nullptr, nullptr, qkvb,
                                        nullptr, nullptr, 1536, 512, 6, 768, 3);

    attn_mfma<<<2048, 256, 0, stream>>>(qkvb, tbl0, tbl1, attno);

    // proj + residual -> d_out (f32) + fused adain2 stats
    gemm256<1><<<256, 512, 0, stream>>>(attno, proj_wb, proj_b, x, outf, nullptr,
                                        psum2, psq2, 512, 512, 2, 256, 3);

    stats_fin2<<<16, 256, 0, stream>>>(psum2, psq2, mean2, rstd2);
    adain_kernel<<<16384, 256, 0, stream>>>(outf, s2, mean2, rstd2, xn);

    // mlp1: 1024 tiles, gridN=8
    gemm256<2><<<256, 512, 0, stream>>>(xn, w1b, mlp_b1, nullptr, nullptr, hbuf,
                                        nullptr, nullptr, 2048, 512, 8, 1024, 3);
    // mlp2: 256 tiles, gridN=2, K=2048 (nt=32)
    gemm256<3><<<256, 512, 0, stream>>>(hbuf, w2b, mlp_b2, nullptr, outf, nullptr,
                                        nullptr, nullptr, 512, 2048, 2, 256, 5);
}